// Round 1
// baseline (154.036 us; speedup 1.0000x reference)
//
#include <hip/hip_runtime.h>
#include <cmath>

#define Bn   4
#define Hn   12
#define BH   48          // B*H
#define Nn   8192
#define Dn   64
#define CH2  16          // chunks per head for phase 2
#define TILE1 32         // rows staged per LDS tile in phase 1

// ---------------- Phase 1: partial KtV = sum_n (k ⊗ v) * rowfac -------------
// rowfac = scale * m^2 / max(||k||, eps)   (since Kf = k*scale*m/||k||, Vm = v*m)
__global__ __launch_bounds__(256) void ktv_partial_kernel(
    const float* __restrict__ K, const float* __restrict__ V,
    const float* __restrict__ mask, float* __restrict__ partial,
    float scale, int ch)
{
    const int chunk = blockIdx.x;
    const int head  = blockIdx.y;
    const int b     = head / Hn;
    const int rowsPer = Nn / ch;
    const int n0    = chunk * rowsPer;

    const float* Kp = K + ((size_t)head * Nn + n0) * Dn;
    const float* Vp = V + ((size_t)head * Nn + n0) * Dn;
    const float* mp = mask + (size_t)b * Nn + n0;

    __shared__ __align__(16) float sK[TILE1 * Dn];
    __shared__ __align__(16) float sV[TILE1 * Dn];
    __shared__ float sF[TILE1];

    const int t  = threadIdx.x;
    const int d4 = (t >> 4) << 2;    // 0..60, thread's 4 d-rows of KtV
    const int e4 = (t & 15) << 2;    // 0..60, thread's 4 e-cols of KtV

    float acc[4][4];
    #pragma unroll
    for (int i = 0; i < 4; ++i)
        #pragma unroll
        for (int j = 0; j < 4; ++j) acc[i][j] = 0.f;

    for (int tb = 0; tb < rowsPer; tb += TILE1) {
        // cooperative load: 32 rows * 64 = 2048 floats per array
        const float4 k0 = *(const float4*)(Kp + (size_t)tb * Dn + t * 4);
        const float4 k1 = *(const float4*)(Kp + (size_t)tb * Dn + (t + 256) * 4);
        const float4 v0 = *(const float4*)(Vp + (size_t)tb * Dn + t * 4);
        const float4 v1 = *(const float4*)(Vp + (size_t)tb * Dn + (t + 256) * 4);
        __syncthreads();   // previous tile fully consumed before overwrite
        *(float4*)(sK + t * 4)         = k0;
        *(float4*)(sK + (t + 256) * 4) = k1;
        *(float4*)(sV + t * 4)         = v0;
        *(float4*)(sV + (t + 256) * 4) = v1;

        // row sum-of-squares: k0 -> row t/16, k1 -> row 16 + t/16
        float ss0 = k0.x*k0.x + k0.y*k0.y + k0.z*k0.z + k0.w*k0.w;
        float ss1 = k1.x*k1.x + k1.y*k1.y + k1.z*k1.z + k1.w*k1.w;
        #pragma unroll
        for (int off = 1; off < 16; off <<= 1) {
            ss0 += __shfl_xor(ss0, off, 64);
            ss1 += __shfl_xor(ss1, off, 64);
        }
        if ((t & 15) == 0) {
            const int r0 = t >> 4;                 // 0..15
            const float m0 = mp[tb + r0];
            const float m1 = mp[tb + 16 + r0];
            sF[r0]      = scale * m0 * m0 / fmaxf(sqrtf(ss0), 1e-12f);
            sF[16 + r0] = scale * m1 * m1 / fmaxf(sqrtf(ss1), 1e-12f);
        }
        __syncthreads();

        #pragma unroll 8
        for (int r = 0; r < TILE1; ++r) {
            const float rf = sF[r];
            const float4 a  = *(const float4*)(sK + r * Dn + d4);
            const float4 bb = *(const float4*)(sV + r * Dn + e4);
            const float ka[4] = {a.x * rf, a.y * rf, a.z * rf, a.w * rf};
            const float vb[4] = {bb.x, bb.y, bb.z, bb.w};
            #pragma unroll
            for (int i = 0; i < 4; ++i)
                #pragma unroll
                for (int j = 0; j < 4; ++j)
                    acc[i][j] = fmaf(ka[i], vb[j], acc[i][j]);
        }
    }

    float* pp = partial + (size_t)(head * ch + chunk) * (Dn * Dn);
    #pragma unroll
    for (int i = 0; i < 4; ++i)
        *(float4*)(pp + (d4 + i) * Dn + e4) =
            make_float4(acc[i][0], acc[i][1], acc[i][2], acc[i][3]);
}

// ---------------- Phase 1b: reduce partials over chunks ---------------------
__global__ __launch_bounds__(256) void ktv_reduce_kernel(
    const float* __restrict__ partial, float* __restrict__ ktv, int ch)
{
    const int head = blockIdx.y;
    const int e = blockIdx.x * 256 + threadIdx.x;          // 0..4095
    const float* pp = partial + (size_t)head * ch * (Dn * Dn) + e;
    float s = 0.f;
    for (int c = 0; c < ch; ++c) s += pp[(size_t)c * (Dn * Dn)];
    ktv[(size_t)head * (Dn * Dn) + e] = s;
}

// ---------------- Phase 2: Out = (normalize(Q)*scale) @ KtV -----------------
__global__ __launch_bounds__(256) void qktv_kernel(
    const float* __restrict__ Q, const float* __restrict__ ktv,
    float* __restrict__ out, float scale)
{
    const int chunk = blockIdx.x;        // 0..CH2-1
    const int head  = blockIdx.y;
    const int rowsPer = Nn / CH2;        // 512
    const int n0    = chunk * rowsPer;

    const float* Qp = Q   + ((size_t)head * Nn + n0) * Dn;
    float*       Op = out + ((size_t)head * Nn + n0) * Dn;

    __shared__ __align__(16) float sKtV[Dn * Dn];
    __shared__ __align__(16) float sQT[Dn * Dn];   // transposed + XOR-swizzled
    __shared__ __align__(16) float sInv[Dn];

    const int t = threadIdx.x;

    {   // stage KtV once per block
        const float* kp = ktv + (size_t)head * (Dn * Dn);
        #pragma unroll
        for (int u = 0; u < 4; ++u) {
            const int f = t + u * 256;
            *(float4*)(sKtV + f * 4) = *(const float4*)(kp + f * 4);
        }
    }

    const int r4 = (t >> 4) << 2;   // thread's 4 output rows within the tile
    const int e4 = (t & 15) << 2;   // thread's 4 output cols

    for (int tb = 0; tb < rowsPer; tb += 64) {
        __syncthreads();   // sKtV staged / previous tile's sQT consumed

        // load 64x64 Q tile, compute row norms, store transposed (swizzled)
        #pragma unroll
        for (int u = 0; u < 4; ++u) {
            const int f   = t + u * 256;
            const int row = f >> 4;              // 0..63
            const int c4  = (f & 15) << 2;
            const float4 q = *(const float4*)(Qp + (size_t)tb * Dn + f * 4);
            float ss = q.x*q.x + q.y*q.y + q.z*q.z + q.w*q.w;
            #pragma unroll
            for (int off = 1; off < 16; off <<= 1) ss += __shfl_xor(ss, off, 64);
            if ((t & 15) == 0) sInv[row] = scale / fmaxf(sqrtf(ss), 1e-12f);
            const float qa[4] = {q.x, q.y, q.z, q.w};
            #pragma unroll
            for (int i = 0; i < 4; ++i) {
                const int c   = c4 + i;
                const int rsw = row ^ (((c >> 2) & 7) << 2);  // break bank stride
                sQT[c * Dn + rsw] = qa[i];
            }
        }
        __syncthreads();

        const float4 inv4 = *(const float4*)(sInv + r4);
        float acc[4][4];
        #pragma unroll
        for (int i = 0; i < 4; ++i)
            #pragma unroll
            for (int j = 0; j < 4; ++j) acc[i][j] = 0.f;

        #pragma unroll 8
        for (int d = 0; d < Dn; ++d) {
            const int s = ((d >> 2) & 7) << 2;
            const float4 a  = *(const float4*)(sQT + d * Dn + (r4 ^ s));
            const float4 bb = *(const float4*)(sKtV + d * Dn + e4);
            const float ka[4] = {a.x * inv4.x, a.y * inv4.y, a.z * inv4.z, a.w * inv4.w};
            const float vb[4] = {bb.x, bb.y, bb.z, bb.w};
            #pragma unroll
            for (int i = 0; i < 4; ++i)
                #pragma unroll
                for (int j = 0; j < 4; ++j)
                    acc[i][j] = fmaf(ka[i], vb[j], acc[i][j]);
        }

        #pragma unroll
        for (int i = 0; i < 4; ++i)
            *(float4*)(Op + (size_t)(tb + r4 + i) * Dn + e4) =
                make_float4(acc[i][0], acc[i][1], acc[i][2], acc[i][3]);
    }
}

extern "C" void kernel_launch(void* const* d_in, const int* in_sizes, int n_in,
                              void* d_out, int out_size, void* d_ws, size_t ws_size,
                              hipStream_t stream)
{
    const float* Q    = (const float*)d_in[0];
    const float* K    = (const float*)d_in[1];
    const float* V    = (const float*)d_in[2];
    const float* mask = (const float*)d_in[3];
    float* out = (float*)d_out;

    const float scale = 1.0f / sqrtf(sqrtf((float)Nn));

    // workspace: [ ktv final: BH*64*64 f32 ][ partials: BH*ch*64*64 f32 ]
    int ch = 32;
    while (ch > 1 &&
           (size_t)(BH) * (size_t)(Dn * Dn) * (size_t)(1 + ch) * 4 > ws_size)
        ch >>= 1;

    float* ktv     = (float*)d_ws;
    float* partial = ktv + (size_t)BH * Dn * Dn;

    ktv_partial_kernel<<<dim3(ch, BH), 256, 0, stream>>>(K, V, mask, partial, scale, ch);
    ktv_reduce_kernel<<<dim3((Dn * Dn) / 256, BH), 256, 0, stream>>>(partial, ktv, ch);
    qktv_kernel<<<dim3(CH2, BH), 256, 0, stream>>>(Q, ktv, out, scale);
}

// Round 2
// 143.958 us; speedup vs baseline: 1.0700x; 1.0700x over previous
//
#include <hip/hip_runtime.h>
#include <cmath>

#define Bn 4
#define Hn 12
#define BH 48
#define Nn 8192
#define Dn 64
#define T1 32

// ---------------- Phase 1: partial KtV = sum_n rf * (k ⊗ v) -----------------
// rf = scale * m^2 / max(||k||, eps); folded into sK at staging time.
__global__ __launch_bounds__(256) void ktv_partial_kernel(
    const float* __restrict__ K, const float* __restrict__ V,
    const float* __restrict__ mask, float* __restrict__ partial,
    float scale, int ch)
{
    const int chunk = blockIdx.x, head = blockIdx.y;
    const int b = head / Hn;
    const int rowsPer = Nn / ch;
    const int n0 = chunk * rowsPer;
    const float* Kp = K + ((size_t)head * Nn + n0) * Dn;
    const float* Vp = V + ((size_t)head * Nn + n0) * Dn;
    const float* mp = mask + (size_t)b * Nn + n0;

    __shared__ __align__(16) float sm[2 * T1 * Dn];   // 16 KB: sK | sV
    float* sK = sm;
    float* sV = sm + T1 * Dn;

    const int t = threadIdx.x;
    const int w = t >> 6;            // wave 0..3
    const int lane = t & 63;
    const int d8 = ((lane >> 3) & 7) << 3;   // 8 KtV rows (d)
    const int e8 = (lane & 7) << 3;          // 8 KtV cols (e)

    const int ra = t >> 4;           // staging row 0..15
    const int rb = ra + 16;
    const int c4 = (t & 15) << 2;

    float acc[8][8];
    #pragma unroll
    for (int i = 0; i < 8; ++i)
        #pragma unroll
        for (int j = 0; j < 8; ++j) acc[i][j] = 0.f;

    // prologue loads (tile 0)
    float4 k0 = *(const float4*)(Kp + ra * Dn + c4);
    float4 k1 = *(const float4*)(Kp + rb * Dn + c4);
    float4 v0 = *(const float4*)(Vp + ra * Dn + c4);
    float4 v1 = *(const float4*)(Vp + rb * Dn + c4);
    float m0 = mp[ra], m1 = mp[rb];

    const int ntiles = rowsPer / T1;
    for (int tt = 0; tt < ntiles; ++tt) {
        float ss0 = k0.x*k0.x + k0.y*k0.y + k0.z*k0.z + k0.w*k0.w;
        float ss1 = k1.x*k1.x + k1.y*k1.y + k1.z*k1.z + k1.w*k1.w;
        #pragma unroll
        for (int off = 1; off < 16; off <<= 1) {
            ss0 += __shfl_xor(ss0, off, 64);
            ss1 += __shfl_xor(ss1, off, 64);
        }
        const float rf0 = scale * m0 * m0 / fmaxf(sqrtf(ss0), 1e-12f);
        const float rf1 = scale * m1 * m1 / fmaxf(sqrtf(ss1), 1e-12f);

        __syncthreads();   // previous tile fully consumed
        *(float4*)(sK + ra * Dn + c4) = make_float4(k0.x*rf0, k0.y*rf0, k0.z*rf0, k0.w*rf0);
        *(float4*)(sK + rb * Dn + c4) = make_float4(k1.x*rf1, k1.y*rf1, k1.z*rf1, k1.w*rf1);
        *(float4*)(sV + ra * Dn + c4) = v0;
        *(float4*)(sV + rb * Dn + c4) = v1;
        __syncthreads();

        // prefetch next tile while this tile's FMA runs
        if (tt + 1 < ntiles) {
            const float* Kn = Kp + (size_t)(tt + 1) * T1 * Dn;
            const float* Vn = Vp + (size_t)(tt + 1) * T1 * Dn;
            k0 = *(const float4*)(Kn + ra * Dn + c4);
            k1 = *(const float4*)(Kn + rb * Dn + c4);
            v0 = *(const float4*)(Vn + ra * Dn + c4);
            v1 = *(const float4*)(Vn + rb * Dn + c4);
            m0 = mp[(tt + 1) * T1 + ra];
            m1 = mp[(tt + 1) * T1 + rb];
        }

        const int rbase = w << 3;    // this wave's 8 rows of the tile
        #pragma unroll
        for (int r = 0; r < 8; ++r) {
            const float* kr = sK + (rbase + r) * Dn;
            const float* vr = sV + (rbase + r) * Dn;
            const float4 a0 = *(const float4*)(kr + d8);
            const float4 a1 = *(const float4*)(kr + d8 + 4);
            const float4 b0 = *(const float4*)(vr + e8);
            const float4 b1 = *(const float4*)(vr + e8 + 4);
            const float ka[8] = {a0.x,a0.y,a0.z,a0.w,a1.x,a1.y,a1.z,a1.w};
            const float vb[8] = {b0.x,b0.y,b0.z,b0.w,b1.x,b1.y,b1.z,b1.w};
            #pragma unroll
            for (int i = 0; i < 8; ++i)
                #pragma unroll
                for (int j = 0; j < 8; ++j)
                    acc[i][j] = fmaf(ka[i], vb[j], acc[i][j]);
        }
    }

    // cross-wave reduce into sm (fixed order -> deterministic)
    __syncthreads();
    #pragma unroll
    for (int ww = 0; ww < 4; ++ww) {
        if (w == ww) {
            #pragma unroll
            for (int i = 0; i < 8; ++i) {
                float* p = sm + (d8 + i) * Dn + e8;
                if (ww == 0) {
                    *(float4*)p       = make_float4(acc[i][0], acc[i][1], acc[i][2], acc[i][3]);
                    *(float4*)(p + 4) = make_float4(acc[i][4], acc[i][5], acc[i][6], acc[i][7]);
                } else {
                    const float4 c0 = *(const float4*)p;
                    const float4 c1 = *(const float4*)(p + 4);
                    *(float4*)p       = make_float4(c0.x+acc[i][0], c0.y+acc[i][1], c0.z+acc[i][2], c0.w+acc[i][3]);
                    *(float4*)(p + 4) = make_float4(c1.x+acc[i][4], c1.y+acc[i][5], c1.z+acc[i][6], c1.w+acc[i][7]);
                }
            }
        }
        __syncthreads();
    }

    float* pp = partial + (size_t)(head * ch + chunk) * (Dn * Dn);
    #pragma unroll
    for (int u = 0; u < 4; ++u) {
        const int f = t + u * 256;
        *(float4*)(pp + f * 4) = *(const float4*)(sm + f * 4);
    }
}

// ---------------- Phase 1b: reduce partials over chunks ---------------------
__global__ __launch_bounds__(256) void ktv_reduce_kernel(
    const float* __restrict__ partial, float* __restrict__ ktv, int ch)
{
    const int head = blockIdx.y;
    const int e = blockIdx.x * 256 + threadIdx.x;          // 0..4095
    const float* pp = partial + (size_t)head * ch * (Dn * Dn) + e;
    float s = 0.f;
    for (int c = 0; c < ch; ++c) s += pp[(size_t)c * (Dn * Dn)];
    ktv[(size_t)head * (Dn * Dn) + e] = s;
}

// ---------------- Phase 2: Out[n,e] = inv(n) * sum_d q[n,d]*KtV[d,e] --------
// inv applied once at the end; Q read direct from global (row-contiguous).
__global__ __launch_bounds__(256) void qktv_kernel(
    const float* __restrict__ Q, const float* __restrict__ ktv,
    float* __restrict__ out, float scale, int ch2)
{
    const int chunk = blockIdx.x, head = blockIdx.y;
    const int rowsPer = Nn / ch2;
    const int n0 = chunk * rowsPer;
    const float* Qp = Q + ((size_t)head * Nn + n0) * Dn;
    float* Op = out + ((size_t)head * Nn + n0) * Dn;

    __shared__ __align__(16) float sB[Dn * Dn];   // KtV, 16 KB

    const int t = threadIdx.x;
    const int w = t >> 6;
    const int lane = t & 63;
    const int r8 = ((lane >> 3) & 7) << 3;   // 8 output rows
    const int e8 = (lane & 7) << 3;          // 8 output cols

    {
        const float* kp = ktv + (size_t)head * (Dn * Dn);
        #pragma unroll
        for (int u = 0; u < 4; ++u) {
            const int f = t + u * 256;
            *(float4*)(sB + f * 4) = *(const float4*)(kp + f * 4);
        }
    }
    __syncthreads();   // only barrier in this kernel

    const int ntiles = rowsPer / 64;
    for (int tile = w; tile < ntiles; tile += 4) {
        const float* Qt = Qp + (size_t)tile * 64 * Dn;
        float* Ot = Op + (size_t)tile * 64 * Dn;

        float acc[8][8];
        float ssq[8];
        #pragma unroll
        for (int i = 0; i < 8; ++i) {
            ssq[i] = 0.f;
            #pragma unroll
            for (int j = 0; j < 8; ++j) acc[i][j] = 0.f;
        }

        for (int d0 = 0; d0 < Dn; d0 += 4) {
            float4 q[8];
            #pragma unroll
            for (int i = 0; i < 8; ++i)
                q[i] = *(const float4*)(Qt + (size_t)(r8 + i) * Dn + d0);
            #pragma unroll
            for (int i = 0; i < 8; ++i)
                ssq[i] += q[i].x*q[i].x + q[i].y*q[i].y + q[i].z*q[i].z + q[i].w*q[i].w;

#define DSTEP(JJ, COMP)                                                        \
            {                                                                  \
                const float4 b0 = *(const float4*)(sB + (d0 + JJ) * Dn + e8);  \
                const float4 b1 = *(const float4*)(sB + (d0 + JJ) * Dn + e8 + 4); \
                const float vb[8] = {b0.x,b0.y,b0.z,b0.w,b1.x,b1.y,b1.z,b1.w}; \
                _Pragma("unroll")                                              \
                for (int i = 0; i < 8; ++i) {                                  \
                    const float qa = q[i].COMP;                                \
                    _Pragma("unroll")                                          \
                    for (int j = 0; j < 8; ++j)                                \
                        acc[i][j] = fmaf(qa, vb[j], acc[i][j]);                \
                }                                                              \
            }
            DSTEP(0, x) DSTEP(1, y) DSTEP(2, z) DSTEP(3, w)
#undef DSTEP
        }

        #pragma unroll
        for (int i = 0; i < 8; ++i) {
            const float inv = scale / fmaxf(sqrtf(ssq[i]), 1e-12f);
            float* op = Ot + (size_t)(r8 + i) * Dn + e8;
            *(float4*)op       = make_float4(acc[i][0]*inv, acc[i][1]*inv, acc[i][2]*inv, acc[i][3]*inv);
            *(float4*)(op + 4) = make_float4(acc[i][4]*inv, acc[i][5]*inv, acc[i][6]*inv, acc[i][7]*inv);
        }
    }
}

extern "C" void kernel_launch(void* const* d_in, const int* in_sizes, int n_in,
                              void* d_out, int out_size, void* d_ws, size_t ws_size,
                              hipStream_t stream)
{
    const float* Q    = (const float*)d_in[0];
    const float* K    = (const float*)d_in[1];
    const float* V    = (const float*)d_in[2];
    const float* mask = (const float*)d_in[3];
    float* out = (float*)d_out;

    const float scale = 1.0f / sqrtf(sqrtf((float)Nn));

    int ch = 16;
    while (ch > 1 &&
           (size_t)(BH) * (size_t)(Dn * Dn) * (size_t)(1 + ch) * 4 > ws_size)
        ch >>= 1;

    float* ktv     = (float*)d_ws;
    float* partial = ktv + (size_t)BH * Dn * Dn;

    ktv_partial_kernel<<<dim3(ch, BH), 256, 0, stream>>>(K, V, mask, partial, scale, ch);
    ktv_reduce_kernel<<<dim3((Dn * Dn) / 256, BH), 256, 0, stream>>>(partial, ktv, ch);
    qktv_kernel<<<dim3(16, BH), 256, 0, stream>>>(Q, ktv, out, scale, 16);
}

// Round 3
// 100.606 us; speedup vs baseline: 1.5311x; 1.4309x over previous
//
#include <hip/hip_runtime.h>
#include <cmath>

#define Bn 4
#define Hn 12
#define BH 48
#define Nn 8192
#define Dn 64

typedef float f32x4 __attribute__((ext_vector_type(4)));
typedef short bf16x8 __attribute__((ext_vector_type(8)));

__device__ __forceinline__ int swz(int d) { return ((d >> 2) & 7) << 3; }

// v_cvt_pk_bf16_f32: D[15:0]=bf16(lo), D[31:16]=bf16(hi)  (RNE)
__device__ __forceinline__ unsigned cvt_pk_bf16(float lo, float hi) {
    unsigned r;
    asm("v_cvt_pk_bf16_f32 %0, %1, %2" : "=v"(r) : "v"(lo), "v"(hi));
    return r;
}

// ---------------- Phase 1: partial KtV^T[e][d] = sum_n (rf*k)[n,d] * v[n,e] --
// rf = scale * m^2 / max(||k||, eps).  MFMA: A = V^T (rows e), B = K' (cols d),
// contraction n.  K,V staged transposed+swizzled in LDS as bf16.
__global__ __launch_bounds__(256) void ktv_kernel(
    const float* __restrict__ K, const float* __restrict__ V,
    const float* __restrict__ mask, float* __restrict__ partial,
    float scale, int ch)
{
    const int chunk = blockIdx.x, head = blockIdx.y;
    const int bb = head / Hn;
    const int rowsPer = Nn / ch;
    const int n0 = chunk * rowsPer;
    const float* Kp = K + ((size_t)head * Nn + n0) * Dn;
    const float* Vp = V + ((size_t)head * Nn + n0) * Dn;
    const float* mp = mask + (size_t)bb * Nn + n0;

    __shared__ __align__(16) ushort sKT[64 * 64];   // [d][n^swz(d)] bf16
    __shared__ __align__(16) ushort sVT[64 * 64];   // [e][n^swz(e)] bf16

    const int t = threadIdx.x;
    const int w = t >> 6, l = t & 63;
    const int g = t >> 4;            // row-group 0..15 (rows 4g..4g+3)
    const int c4 = (t & 15) << 2;    // d base for staging

    f32x4 acc[4] = {{0.f,0.f,0.f,0.f},{0.f,0.f,0.f,0.f},
                    {0.f,0.f,0.f,0.f},{0.f,0.f,0.f,0.f}};

    float4 kr[4], vr[4];
    float mk[4];
    #pragma unroll
    for (int s = 0; s < 4; ++s) {
        kr[s] = *(const float4*)(Kp + (size_t)(4*g + s) * Dn + c4);
        vr[s] = *(const float4*)(Vp + (size_t)(4*g + s) * Dn + c4);
        mk[s] = mp[4*g + s];
    }

    const int ntiles = rowsPer >> 6;          // 64-row tiles
    for (int tt = 0; tt < ntiles; ++tt) {
        float rf[4];
        #pragma unroll
        for (int s = 0; s < 4; ++s) {
            float ss = kr[s].x*kr[s].x + kr[s].y*kr[s].y
                     + kr[s].z*kr[s].z + kr[s].w*kr[s].w;
            #pragma unroll
            for (int off = 1; off < 16; off <<= 1) ss += __shfl_xor(ss, off, 64);
            rf[s] = scale * mk[s] * mk[s] / fmaxf(sqrtf(ss), 1e-12f);
        }

        __syncthreads();                      // previous tile consumed
        const float* krf = (const float*)kr;  // kr[s] comp j -> krf[4s+j]
        const float* vrf = (const float*)vr;
        #pragma unroll
        for (int j = 0; j < 4; ++j) {
            const int d = c4 + j;
            const int base = d * 64;
            const int sw = swz(d);
            const int p0 = (4*g)     ^ sw;    // even; swz only hits bits 3..5
            const int p2 = (4*g + 2) ^ sw;
            *(unsigned*)&sKT[base + p0] = cvt_pk_bf16(krf[j]     * rf[0], krf[4+j]  * rf[1]);
            *(unsigned*)&sKT[base + p2] = cvt_pk_bf16(krf[8+j]   * rf[2], krf[12+j] * rf[3]);
            *(unsigned*)&sVT[base + p0] = cvt_pk_bf16(vrf[j],            vrf[4+j]);
            *(unsigned*)&sVT[base + p2] = cvt_pk_bf16(vrf[8+j],          vrf[12+j]);
        }
        __syncthreads();

        if (tt + 1 < ntiles) {                // prefetch under MFMA
            const float* Kn = Kp + (size_t)(tt + 1) * 64 * Dn;
            const float* Vn = Vp + (size_t)(tt + 1) * 64 * Dn;
            #pragma unroll
            for (int s = 0; s < 4; ++s) {
                kr[s] = *(const float4*)(Kn + (size_t)(4*g + s) * Dn + c4);
                vr[s] = *(const float4*)(Vn + (size_t)(4*g + s) * Dn + c4);
                mk[s] = mp[(tt + 1) * 64 + 4*g + s];
            }
        }

        // wave w owns e-strip [16w,16w+16); 4 d-panels; contraction in 2 halves
        const int e   = (w << 4) + (l & 15);
        const int nsl = (l >> 4) << 3;        // k-slice start within 32-half
        const int swe = swz(e);
        #pragma unroll
        for (int h = 0; h < 2; ++h) {
            const bf16x8 a = *(const bf16x8*)&sVT[e * 64 + ((h*32 + nsl) ^ swe)];
            #pragma unroll
            for (int P = 0; P < 4; ++P) {
                const int d = (P << 4) + (l & 15);
                const bf16x8 bq = *(const bf16x8*)&sKT[d * 64 + ((h*32 + nsl) ^ swz(d))];
                acc[P] = __builtin_amdgcn_mfma_f32_16x16x32_bf16(a, bq, acc[P], 0, 0, 0);
            }
        }
    }

    // C layout: col = lane&15, row = 4*(lane>>4)+reg   (HW-verified)
    float* pp = partial + (size_t)(head * ch + chunk) * (Dn * Dn);
    #pragma unroll
    for (int P = 0; P < 4; ++P)
        #pragma unroll
        for (int r = 0; r < 4; ++r)
            pp[((w << 4) + ((l >> 4) << 2) + r) * 64 + (P << 4) + (l & 15)] = acc[P][r];
}

// ---------------- Phase 1b: reduce partials, emit bf16 KtV^T ----------------
__global__ __launch_bounds__(256) void ktv_reduce_kernel(
    const float* __restrict__ partial, ushort* __restrict__ ktvT, int ch)
{
    const int head = blockIdx.y;
    const int e = blockIdx.x * 256 + threadIdx.x;   // 0..4095
    const float* pp = partial + (size_t)head * ch * (Dn * Dn) + e;
    float s = 0.f;
    for (int c = 0; c < ch; ++c) s += pp[(size_t)c * (Dn * Dn)];
    unsigned u = __float_as_uint(s);
    u = (u + 0x7fffu + ((u >> 16) & 1u)) >> 16;     // RNE
    ktvT[(size_t)head * (Dn * Dn) + e] = (ushort)u;
}

// ---------------- Phase 2: Out = (inv(n)*q) @ KtV  (no LDS) -----------------
// A = Q rows (d contiguous), inv-norm folded into A pre-conversion.
// B = KtV^T rows from global (L2-resident, 8 frags hoisted to registers).
__global__ __launch_bounds__(256) void qktv_kernel(
    const float* __restrict__ Q, const ushort* __restrict__ ktvT,
    float* __restrict__ out, float scale)
{
    const int chunk = blockIdx.x, head = blockIdx.y;
    const int n0 = chunk * (Nn / 16);               // 512 rows per block
    const float* Qp = Q + ((size_t)head * Nn + n0) * Dn;
    float* Op = out + ((size_t)head * Nn + n0) * Dn;
    const ushort* kp = ktvT + (size_t)head * (Dn * Dn);

    const int t = threadIdx.x, w = t >> 6, l = t & 63;
    const int lr = l & 15;          // A row-local / B col-local
    const int lg = l >> 4;          // k-group

    bf16x8 bf[4][2];
    #pragma unroll
    for (int E = 0; E < 4; ++E)
        #pragma unroll
        for (int h = 0; h < 2; ++h)
            bf[E][h] = *(const bf16x8*)&kp[(16*E + lr) * 64 + 32*h + 8*lg];

    for (int i = 0; i < 8; ++i) {
        const int strip = i * 4 + w;                // 0..31, 16 rows each
        const float* qrow = Qp + (size_t)(strip * 16 + lr) * Dn;
        const float4 f0 = *(const float4*)(qrow + 8*lg);
        const float4 f1 = *(const float4*)(qrow + 8*lg + 4);
        const float4 f2 = *(const float4*)(qrow + 32 + 8*lg);
        const float4 f3 = *(const float4*)(qrow + 32 + 8*lg + 4);

        float ss = f0.x*f0.x + f0.y*f0.y + f0.z*f0.z + f0.w*f0.w
                 + f1.x*f1.x + f1.y*f1.y + f1.z*f1.z + f1.w*f1.w
                 + f2.x*f2.x + f2.y*f2.y + f2.z*f2.z + f2.w*f2.w
                 + f3.x*f3.x + f3.y*f3.y + f3.z*f3.z + f3.w*f3.w;
        ss += __shfl_xor(ss, 16, 64);
        ss += __shfl_xor(ss, 32, 64);
        const float inv = scale / fmaxf(sqrtf(ss), 1e-12f);

        union { unsigned u[4]; bf16x8 v; } a0, a1;
        a0.u[0] = cvt_pk_bf16(f0.x*inv, f0.y*inv);
        a0.u[1] = cvt_pk_bf16(f0.z*inv, f0.w*inv);
        a0.u[2] = cvt_pk_bf16(f1.x*inv, f1.y*inv);
        a0.u[3] = cvt_pk_bf16(f1.z*inv, f1.w*inv);
        a1.u[0] = cvt_pk_bf16(f2.x*inv, f2.y*inv);
        a1.u[1] = cvt_pk_bf16(f2.z*inv, f2.w*inv);
        a1.u[2] = cvt_pk_bf16(f3.x*inv, f3.y*inv);
        a1.u[3] = cvt_pk_bf16(f3.z*inv, f3.w*inv);

        #pragma unroll
        for (int E = 0; E < 4; ++E) {
            f32x4 c = {0.f, 0.f, 0.f, 0.f};
            c = __builtin_amdgcn_mfma_f32_16x16x32_bf16(a0.v, bf[E][0], c, 0, 0, 0);
            c = __builtin_amdgcn_mfma_f32_16x16x32_bf16(a1.v, bf[E][1], c, 0, 0, 0);
            #pragma unroll
            for (int r = 0; r < 4; ++r)
                Op[(size_t)(strip * 16 + 4*lg + r) * Dn + 16*E + lr] = c[r];
        }
    }
}

extern "C" void kernel_launch(void* const* d_in, const int* in_sizes, int n_in,
                              void* d_out, int out_size, void* d_ws, size_t ws_size,
                              hipStream_t stream)
{
    const float* Q    = (const float*)d_in[0];
    const float* K    = (const float*)d_in[1];
    const float* V    = (const float*)d_in[2];
    const float* mask = (const float*)d_in[3];
    float* out = (float*)d_out;

    const float scale = 1.0f / sqrtf(sqrtf((float)Nn));

    // ws layout: [ ktvT bf16: BH*4096 ushort ][ partial: BH*ch*4096 f32 ]
    const size_t KTV_BYTES = (size_t)BH * Dn * Dn * sizeof(ushort);   // 384 KB
    int ch = 16;
    while (ch > 1 &&
           KTV_BYTES + (size_t)BH * ch * Dn * Dn * 4 > ws_size)
        ch >>= 1;

    ushort* ktvT   = (ushort*)d_ws;
    float* partial = (float*)((char*)d_ws + KTV_BYTES);

    ktv_kernel<<<dim3(ch, BH), 256, 0, stream>>>(K, V, mask, partial, scale, ch);
    ktv_reduce_kernel<<<dim3((Dn * Dn) / 256, BH), 256, 0, stream>>>(partial, ktvT, ch);
    qktv_kernel<<<dim3(16, BH), 256, 0, stream>>>(Q, ktvT, out, scale);
}